// Round 8
// baseline (2500.959 us; speedup 1.0000x reference)
//
#include <hip/hip_runtime.h>
#include <math.h>

// K-means m=100000, n=128, K=128, 15 iters, tol=1e-4 — bit-exact f32 replication
// of the numpy reference arithmetic (verified absmax 0.0 in R3-R7):
//  - dots: sequential in-order FMA chain over d (ascending)
//  - x_sq/c_sq/norm: numpy pairwise-8 pattern
//  - d2 = (x_sq - 2*dot) + c_sq, each op individually rounded (__f*_rn)
//  - argmin: first-min-wins; segment sums: sequential adds in ascending point order
// R8 = R7 with update2T_k's load batch pinned via inline-asm global_load_dwordx4
// into 16 named float4 regs + vmcnt(0) + sched_barrier(0). hipcc refused
// source-level MLP batching 3x (VGPR=20/20/36); asm dests force MLP=16.

#define KC 128
#define ND 128

__device__ __forceinline__ unsigned mapf(float s) {
    unsigned b = __float_as_uint(s);
    return (b & 0x80000000u) ? ~b : (b | 0x80000000u);  // order-preserving f32->u32
}

__device__ __forceinline__ bool is_done(const int* __restrict__ conv, int t) {
    bool d = false;
    for (int j = 0; j < t; ++j) d |= (conv[j] == KC);
    return d;
}

// numpy pairwise-8 combine tree
__device__ __forceinline__ float comb8(const float* r) {
    float t1 = __fadd_rn(__fadd_rn(r[0], r[1]), __fadd_rn(r[2], r[3]));
    float t2 = __fadd_rn(__fadd_rn(r[4], r[5]), __fadd_rn(r[6], r[7]));
    return __fadd_rn(t1, t2);
}

// ---- x_sq per point (once): numpy pairwise-8 over rounded squares ----
__global__ __launch_bounds__(256) void xsq_k(const float* __restrict__ X,
                                             float* __restrict__ xsq, int m) {
    int p = blockIdx.x * 256 + threadIdx.x;
    if (p >= m) return;
    const float* xr = X + (size_t)p * ND;
    float r[8];
#pragma unroll
    for (int j = 0; j < 8; ++j) r[j] = __fmul_rn(xr[j], xr[j]);
    for (int b = 1; b < 16; ++b) {
#pragma unroll
        for (int j = 0; j < 8; ++j) {
            float v = xr[8 * b + j];
            r[j] = __fadd_rn(r[j], __fmul_rn(v, v));
        }
    }
    xsq[p] = comb8(r);
}

// ---- csq of initial centroids ----
__global__ __launch_bounds__(128) void csq0_k(const float* __restrict__ c,
                                              float* __restrict__ csq) {
    int k = threadIdx.x;
    const float* cr = c + k * ND;
    float r[8];
#pragma unroll
    for (int j = 0; j < 8; ++j) r[j] = __fmul_rn(cr[j], cr[j]);
    for (int b = 1; b < 16; ++b) {
#pragma unroll
        for (int j = 0; j < 8; ++j) {
            float v = cr[8 * b + j];
            r[j] = __fadd_rn(r[j], __fmul_rn(v, v));
        }
    }
    csq[k] = comb8(r);
}

// ---- assign: grid ceil(m/128), block 256. One pass, 128pt x 128k tile ----
__global__ __launch_bounds__(256, 3) void assign_k(
    const float* __restrict__ X, const float* __restrict__ cent,
    const float* __restrict__ csq, const float* __restrict__ xsq,
    int* __restrict__ cl, float* __restrict__ cl_out,
    unsigned char* __restrict__ rankA, unsigned char* __restrict__ hist,
    const int* __restrict__ conv, int t, int m, int nch)
{
    if (is_done(conv, t)) return;
    __shared__ float XT[32][128];    // [d'][pt]  16 KB
    __shared__ float CT[128][36];    // [k][d']   18 KB
    __shared__ float csql[128];
    __shared__ unsigned long long mk[128];
    __shared__ int cls[128];

    const int tid = threadIdx.x;
    const int ptg = tid & 31, kg = tid >> 5;
    const int base = blockIdx.x * 128;
    const int row = tid >> 1, hf = tid & 1;      // staging coords

    if (tid < 128) { mk[tid] = ~0ULL; csql[tid] = csq[tid]; }

    const int srow = base + row;
    const float4* xsrc = (const float4*)(X + (size_t)(srow < m ? srow : m - 1) * ND);
    const float4* csrc = (const float4*)(cent + (size_t)row * ND);

    float acc[4][16];
#pragma unroll
    for (int i = 0; i < 4; ++i)
#pragma unroll
        for (int j = 0; j < 16; ++j) acc[i][j] = 0.0f;

    float4 xr[4], cr[4];
#pragma unroll
    for (int q = 0; q < 4; ++q) {                // prefetch chunk 0
        xr[q] = xsrc[hf * 4 + q];
        cr[q] = csrc[hf * 4 + q];
    }

#pragma unroll 1
    for (int c = 0; c < 4; ++c) {
        __syncthreads();                         // prior compute done
#pragma unroll
        for (int q = 0; q < 4; ++q) {            // store regs -> LDS
            const int dp = hf * 16 + 4 * q;      // d' within chunk
            XT[dp + 0][row] = xr[q].x;
            XT[dp + 1][row] = xr[q].y;
            XT[dp + 2][row] = xr[q].z;
            XT[dp + 3][row] = xr[q].w;
            *(float4*)&CT[row][dp] = cr[q];
        }
        __syncthreads();
        if (c < 3) {
#pragma unroll
            for (int q = 0; q < 4; ++q) {        // prefetch chunk c+1
                xr[q] = xsrc[(c + 1) * 8 + hf * 4 + q];
                cr[q] = csrc[(c + 1) * 8 + hf * 4 + q];
            }
        }
#pragma unroll
        for (int c4 = 0; c4 < 8; ++c4) {         // 4 ds per step, ascending
            float4 av[4];
#pragma unroll
            for (int dd = 0; dd < 4; ++dd)
                av[dd] = *(const float4*)&XT[4 * c4 + dd][4 * ptg];
#pragma unroll
            for (int j = 0; j < 16; ++j) {
                const float4 b = *(const float4*)&CT[kg * 16 + j][4 * c4];
#pragma unroll
                for (int i = 0; i < 4; ++i) {
                    float s = acc[i][j];
                    const float a0 = (i == 0) ? av[0].x : (i == 1) ? av[0].y
                                   : (i == 2) ? av[0].z : av[0].w;
                    const float a1 = (i == 0) ? av[1].x : (i == 1) ? av[1].y
                                   : (i == 2) ? av[1].z : av[1].w;
                    const float a2 = (i == 0) ? av[2].x : (i == 1) ? av[2].y
                                   : (i == 2) ? av[2].z : av[2].w;
                    const float a3 = (i == 0) ? av[3].x : (i == 1) ? av[3].y
                                   : (i == 2) ? av[3].z : av[3].w;
                    s = __fmaf_rn(a0, b.x, s);
                    s = __fmaf_rn(a1, b.y, s);
                    s = __fmaf_rn(a2, b.z, s);
                    s = __fmaf_rn(a3, b.w, s);
                    acc[i][j] = s;
                }
            }
        }
    }

    // ---- per-point argmin over this thread's 16 ks, then cross-thread ----
#pragma unroll
    for (int i = 0; i < 4; ++i) {
        const int pt = base + 4 * ptg + i;
        if (pt >= m) continue;
        const float xq = xsq[pt];
        float best = __int_as_float(0x7f800000);
        int bk = 0;
#pragma unroll
        for (int j = 0; j < 16; ++j) {           // ascending k
            const int kk = kg * 16 + j;
            const float d2 =
                __fadd_rn(__fsub_rn(xq, __fmul_rn(2.0f, acc[i][j])), csql[kk]);
            if (d2 < best) { best = d2; bk = kk; }
        }
        const unsigned long long key =
            ((unsigned long long)mapf(best) << 32) | (unsigned)bk;
        atomicMin(&mk[4 * ptg + i], key);
    }
    __syncthreads();
    if (tid < 128) {
        const int pt = base + tid;
        int k = 255;
        if (pt < m) {
            k = (int)(mk[tid] & 0xFFFFFFFFu);
            cl[pt] = k;
            cl_out[pt] = (float)k;
        }
        cls[tid] = k;
    }
    __syncthreads();
    // ---- fused stable rank (waves 0-1) + per-chunk histogram (waves 2-3) ----
    if (tid < 128) {
        const int myc = cls[tid];
        int rank = 0;
        for (int q = 0; q < 128; ++q)
            rank += (q < tid && cls[q] == myc) ? 1 : 0;
        if (base + tid < m) rankA[base + tid] = (unsigned char)rank;
    } else {
        const int c = tid - 128;
        int cnt = 0;
        for (int q = 0; q < 128; ++q)
            cnt += (cls[q] == c) ? 1 : 0;
        hist[(size_t)c * nch + blockIdx.x] = (unsigned char)cnt;
    }
}

// ---- per-cluster prefix over chunks: block k, 256 threads ----
__global__ __launch_bounds__(256) void scan_k(
    const unsigned char* __restrict__ hist, unsigned* __restrict__ cbase,
    int* __restrict__ counts, const int* __restrict__ conv, int t, int nch)
{
    if (is_done(conv, t)) return;
    const int k = blockIdx.x, tid = threadIdx.x;
    const int strip = (nch + 255) >> 8;
    __shared__ int ss[256];
    int s = 0;
    for (int j = 0; j < strip; ++j) {
        int c = tid * strip + j;
        if (c < nch) s += hist[(size_t)k * nch + c];
    }
    ss[tid] = s;
    __syncthreads();
    if (tid == 0) {
        int run = 0;
        for (int i = 0; i < 256; ++i) { int v = ss[i]; ss[i] = run; run += v; }
        counts[k] = run;
    }
    __syncthreads();
    int run = ss[tid];
    for (int j = 0; j < strip; ++j) {
        int c = tid * strip + j;
        if (c < nch) {
            cbase[(size_t)k * nch + c] = (unsigned)run;
            run += hist[(size_t)k * nch + c];
        }
    }
}

// ---- padded offsets + pad-slot fill + tail fill (no memsets) ----
__global__ __launch_bounds__(128) void off_k(
    const int* __restrict__ counts, int* __restrict__ offp,
    int* __restrict__ srcidx, const int* __restrict__ conv, int t, int mcap)
{
    if (is_done(conv, t)) return;
    __shared__ int o[KC + 1];
    if (threadIdx.x == 0) {
        int run = 0;
        for (int k = 0; k < KC; ++k) { o[k] = run; run += (counts[k] + 3) & ~3; }
        o[KC] = run;
        offp[KC] = run;
    }
    __syncthreads();
    const int k = threadIdx.x;
    offp[k] = o[k];
    const int n = counts[k], np = (n + 3) & ~3;
    for (int i = n; i < np; ++i) srcidx[o[k] + i] = -1;
    for (int i = o[KC] + k; i < mcap; i += 128) srcidx[i] = -1;
}

// ---- scatter point ids into padded stable-sorted positions ----
__global__ __launch_bounds__(256) void scatter_k(
    const int* __restrict__ cl, const unsigned char* __restrict__ rankA,
    const unsigned* __restrict__ cbase, const int* __restrict__ offp,
    int* __restrict__ srcidx, const int* __restrict__ conv,
    int t, int m, int nch)
{
    if (is_done(conv, t)) return;
    int p = blockIdx.x * 256 + threadIdx.x;
    if (p >= m) return;
    int c = cl[p];
    int chunk = p >> 7;                          // 128-pt chunks
    srcidx[offp[c] + (int)cbase[(size_t)c * nch + chunk] + rankA[p]] = p;
}

// ---- transpose into XsT[d][j] (column stride mcap), pads -> +0.0 ----
__global__ __launch_bounds__(256) void sortxT_k(
    const float* __restrict__ X, const int* __restrict__ srcidx,
    float* __restrict__ XsT, const int* __restrict__ conv, int t, int mcap)
{
    if (is_done(conv, t)) return;
    __shared__ float T[128 * 132];
    const int tid = threadIdx.x;
    const int j0 = blockIdx.x * 128;
    {
        const int r = tid >> 1, hh = tid & 1;
        const int src = srcidx[j0 + r];
        float4 z = make_float4(0.f, 0.f, 0.f, 0.f);
        const float4* xr = (const float4*)(X + (size_t)(src < 0 ? 0 : src) * ND);
#pragma unroll
        for (int q = 0; q < 16; ++q) {
            float4 v = (src >= 0) ? xr[hh * 16 + q] : z;
            *(float4*)&T[r * 132 + hh * 64 + 4 * q] = v;
        }
    }
    __syncthreads();
    {
        const int d = tid >> 1, hh = tid & 1;
        float* dst = XsT + (size_t)d * mcap + j0 + hh * 64;
#pragma unroll
        for (int q = 0; q < 16; ++q) {
            int j = hh * 64 + 4 * q;
            float4 v;
            v.x = T[(j + 0) * 132 + d];
            v.y = T[(j + 1) * 132 + d];
            v.z = T[(j + 2) * 132 + d];
            v.w = T[(j + 3) * 132 + d];
            *(float4*)&dst[4 * q] = v;
        }
    }
}

// ---- shared epilogue of the update kernels ----
__device__ __forceinline__ void update_epi(
    int k, int d, int n, float s,
    const float* __restrict__ cent_old, float* __restrict__ cent_new,
    float* __restrict__ csq_new, int* __restrict__ conv, int t)
{
    const float old = cent_old[k * ND + d];
    const float nv = (n > 0) ? __fdiv_rn(s, (float)n) : old;
    cent_new[k * ND + d] = nv;

    __shared__ float sv[128], dv[128], rr[8], dd[8];
    sv[d] = nv;
    dv[d] = __fsub_rn(nv, old);
    __syncthreads();
    if (d < 8) {
        float r = __fmul_rn(sv[d], sv[d]);
        float q = __fmul_rn(dv[d], dv[d]);
        for (int b = 1; b < 16; ++b) {
            float c1 = sv[8 * b + d], c2 = dv[8 * b + d];
            r = __fadd_rn(r, __fmul_rn(c1, c1));
            q = __fadd_rn(q, __fmul_rn(c2, c2));
        }
        rr[d] = r; dd[d] = q;
    }
    __syncthreads();
    if (d == 0) {
        csq_new[k] = comb8(rr);
        float ns = comb8(dd);
        if (__fsqrt_rn(ns) < 1e-4f) atomicAdd(&conv[t], 1);
    }
}

// asm-pinned 16-byte load: distinct named dest regs the compiler cannot sink
#define LDA(i, off_) \
    asm volatile("global_load_dwordx4 %0, %1, off offset:" #off_ \
                 : "=v"(v##i) : "v"(p))

// ---- segment mean from transposed sorted X: asm-MLP float4 streams ----
__global__ __launch_bounds__(128) void update2T_k(
    const float* __restrict__ XsT, const int* __restrict__ offp,
    const int* __restrict__ counts, const float* __restrict__ cent_old,
    float* __restrict__ cent_new, float* __restrict__ csq_new,
    int* __restrict__ conv, int t, int mcap)
{
    if (is_done(conv, t)) return;
    const int k = blockIdx.x, d = threadIdx.x;
    const int n = counts[k];
    const int nq = ((n + 3) & ~3) >> 2;          // npad in float4s
    const float4* col = (const float4*)(XsT + (size_t)d * mcap + offp[k]);
    float s = 0.0f;
    int i4 = 0;
#pragma unroll 1
    for (; i4 + 16 <= nq; i4 += 16) {            // MLP=16, pinned in regs
        const float4* p = col + i4;
        float4 v0, v1, v2, v3, v4, v5, v6, v7;
        float4 v8, v9, v10, v11, v12, v13, v14, v15;
        LDA(0, 0);    LDA(1, 16);   LDA(2, 32);   LDA(3, 48);
        LDA(4, 64);   LDA(5, 80);   LDA(6, 96);   LDA(7, 112);
        LDA(8, 128);  LDA(9, 144);  LDA(10, 160); LDA(11, 176);
        LDA(12, 192); LDA(13, 208); LDA(14, 224); LDA(15, 240);
        asm volatile("s_waitcnt vmcnt(0)" ::: "memory");
        __builtin_amdgcn_sched_barrier(0);       // rule #18: no hoist past wait
        s = __fadd_rn(s, v0.x);  s = __fadd_rn(s, v0.y);
        s = __fadd_rn(s, v0.z);  s = __fadd_rn(s, v0.w);
        s = __fadd_rn(s, v1.x);  s = __fadd_rn(s, v1.y);
        s = __fadd_rn(s, v1.z);  s = __fadd_rn(s, v1.w);
        s = __fadd_rn(s, v2.x);  s = __fadd_rn(s, v2.y);
        s = __fadd_rn(s, v2.z);  s = __fadd_rn(s, v2.w);
        s = __fadd_rn(s, v3.x);  s = __fadd_rn(s, v3.y);
        s = __fadd_rn(s, v3.z);  s = __fadd_rn(s, v3.w);
        s = __fadd_rn(s, v4.x);  s = __fadd_rn(s, v4.y);
        s = __fadd_rn(s, v4.z);  s = __fadd_rn(s, v4.w);
        s = __fadd_rn(s, v5.x);  s = __fadd_rn(s, v5.y);
        s = __fadd_rn(s, v5.z);  s = __fadd_rn(s, v5.w);
        s = __fadd_rn(s, v6.x);  s = __fadd_rn(s, v6.y);
        s = __fadd_rn(s, v6.z);  s = __fadd_rn(s, v6.w);
        s = __fadd_rn(s, v7.x);  s = __fadd_rn(s, v7.y);
        s = __fadd_rn(s, v7.z);  s = __fadd_rn(s, v7.w);
        s = __fadd_rn(s, v8.x);  s = __fadd_rn(s, v8.y);
        s = __fadd_rn(s, v8.z);  s = __fadd_rn(s, v8.w);
        s = __fadd_rn(s, v9.x);  s = __fadd_rn(s, v9.y);
        s = __fadd_rn(s, v9.z);  s = __fadd_rn(s, v9.w);
        s = __fadd_rn(s, v10.x); s = __fadd_rn(s, v10.y);
        s = __fadd_rn(s, v10.z); s = __fadd_rn(s, v10.w);
        s = __fadd_rn(s, v11.x); s = __fadd_rn(s, v11.y);
        s = __fadd_rn(s, v11.z); s = __fadd_rn(s, v11.w);
        s = __fadd_rn(s, v12.x); s = __fadd_rn(s, v12.y);
        s = __fadd_rn(s, v12.z); s = __fadd_rn(s, v12.w);
        s = __fadd_rn(s, v13.x); s = __fadd_rn(s, v13.y);
        s = __fadd_rn(s, v13.z); s = __fadd_rn(s, v13.w);
        s = __fadd_rn(s, v14.x); s = __fadd_rn(s, v14.y);
        s = __fadd_rn(s, v14.z); s = __fadd_rn(s, v14.w);
        s = __fadd_rn(s, v15.x); s = __fadd_rn(s, v15.y);
        s = __fadd_rn(s, v15.z); s = __fadd_rn(s, v15.w);
    }
#pragma unroll 1
    for (; i4 + 4 <= nq; i4 += 4) {              // 4-deep tail
        const float4* p = col + i4;
        float4 v0, v1, v2, v3;
        LDA(0, 0); LDA(1, 16); LDA(2, 32); LDA(3, 48);
        asm volatile("s_waitcnt vmcnt(0)" ::: "memory");
        __builtin_amdgcn_sched_barrier(0);
        s = __fadd_rn(s, v0.x); s = __fadd_rn(s, v0.y);
        s = __fadd_rn(s, v0.z); s = __fadd_rn(s, v0.w);
        s = __fadd_rn(s, v1.x); s = __fadd_rn(s, v1.y);
        s = __fadd_rn(s, v1.z); s = __fadd_rn(s, v1.w);
        s = __fadd_rn(s, v2.x); s = __fadd_rn(s, v2.y);
        s = __fadd_rn(s, v2.z); s = __fadd_rn(s, v2.w);
        s = __fadd_rn(s, v3.x); s = __fadd_rn(s, v3.y);
        s = __fadd_rn(s, v3.z); s = __fadd_rn(s, v3.w);
    }
#pragma unroll 1
    for (; i4 < nq; ++i4) {
        float4 v = col[i4];
        s = __fadd_rn(s, v.x); s = __fadd_rn(s, v.y);
        s = __fadd_rn(s, v.z); s = __fadd_rn(s, v.w);
    }
    update_epi(k, d, n, s, cent_old, cent_new, csq_new, conv, t);
}

// ---- fallback (small ws): gather via srcidx ----
__global__ __launch_bounds__(128) void updateg_k(
    const float* __restrict__ X, const int* __restrict__ srcidx,
    const int* __restrict__ offp, const int* __restrict__ counts,
    const float* __restrict__ cent_old, float* __restrict__ cent_new,
    float* __restrict__ csq_new, int* __restrict__ conv, int t)
{
    if (is_done(conv, t)) return;
    const int k = blockIdx.x, d = threadIdx.x;
    const int n = counts[k];
    const int npad = (n + 3) & ~3;
    const int* si = srcidx + offp[k];
    float s = 0.0f;
#pragma unroll 1
    for (int i0 = 0; i0 < npad; i0 += 32) {
        float v[32];
#pragma unroll
        for (int j = 0; j < 32; ++j) {
            int idx = i0 + j;
            int src = idx < npad ? si[idx] : -1;
            float x = X[(size_t)(src < 0 ? 0 : src) * ND + d];
            v[j] = (src >= 0 && idx < npad) ? x : 0.0f;
        }
        __builtin_amdgcn_sched_barrier(0);
#pragma unroll
        for (int j = 0; j < 32; ++j) s = __fadd_rn(s, v[j]);
    }
    update_epi(k, d, n, s, cent_old, cent_new, csq_new, conv, t);
}

// ---- final: pick the right centroid buffer ----
__global__ __launch_bounds__(256) void final_k(
    const float* __restrict__ cent_bufs, const int* __restrict__ conv,
    float* __restrict__ out)
{
    int tf = 15;
    for (int j = 14; j >= 0; --j)
        if (conv[j] == KC) tf = j;
    const float* c = cent_bufs + (size_t)(tf & 1) * KC * ND;
    int i = blockIdx.x * 256 + threadIdx.x;
    out[i] = c[i];
}

extern "C" void kernel_launch(void* const* d_in, const int* in_sizes, int n_in,
                              void* d_out, int out_size, void* d_ws, size_t ws_size,
                              hipStream_t stream) {
    const float* X = (const float*)d_in[0];
    const float* cent0 = (const float*)d_in[1];
    float* outF = (float*)d_out;
    const int m = in_sizes[0] / ND;              // 100000
    const int nch = (m + 127) / 128;             // 782 chunks of 128 pts
    const int mcap = ((m + 4 * KC) + 127) & ~127;  // padded slots, mult of 128

    unsigned char* w = (unsigned char*)d_ws;
    float* centb = (float*)w;            w += (size_t)2 * KC * ND * 4;
    float* csqb = (float*)w;             w += (size_t)2 * KC * 4;
    float* xsq = (float*)w;              w += (size_t)m * 4;
    int* cl = (int*)w;                   w += (size_t)m * 4;
    int* srcidx = (int*)w;               w += (size_t)mcap * 4;
    unsigned* cbase = (unsigned*)w;      w += (size_t)KC * nch * 4;
    int* offp = (int*)w;                 w += 132 * 4;
    int* counts = (int*)w;               w += KC * 4;
    int* conv = (int*)w;                 w += 16 * 4;
    unsigned char* rankA = w;            w += (size_t)m;
    unsigned char* hist = w;             w += (size_t)KC * nch;
    w = (unsigned char*)(((uintptr_t)w + 15) & ~(uintptr_t)15);
    float* XsT = (float*)w;              // ND * mcap floats (~51.5 MB)
    const bool use_t =
        ((unsigned char*)XsT - (unsigned char*)d_ws) + (size_t)ND * mcap * 4 <= ws_size;

    hipMemsetAsync(conv, 0, 16 * sizeof(int), stream);
    hipMemcpyAsync(centb, cent0, KC * ND * sizeof(float),
                   hipMemcpyDeviceToDevice, stream);
    csq0_k<<<1, 128, 0, stream>>>(centb, csqb);

    const int gp = (m + 255) / 256;              // 391
    const int ga = (m + 127) / 128;              // 782
    const int gt = mcap / 128;                   // 786
    xsq_k<<<gp, 256, 0, stream>>>(X, xsq, m);

    for (int t = 0; t < 15; ++t) {
        const float* cc = centb + (size_t)(t & 1) * KC * ND;
        float* cn = centb + (size_t)((t + 1) & 1) * KC * ND;
        const float* cs = csqb + (t & 1) * KC;
        float* csn = csqb + ((t + 1) & 1) * KC;

        assign_k<<<ga, 256, 0, stream>>>(X, cc, cs, xsq, cl, outF + KC * ND,
                                         rankA, hist, conv, t, m, nch);
        scan_k<<<KC, 256, 0, stream>>>(hist, cbase, counts, conv, t, nch);
        off_k<<<1, 128, 0, stream>>>(counts, offp, srcidx, conv, t, mcap);
        scatter_k<<<gp, 256, 0, stream>>>(cl, rankA, cbase, offp, srcidx,
                                          conv, t, m, nch);
        if (use_t) {
            sortxT_k<<<gt, 256, 0, stream>>>(X, srcidx, XsT, conv, t, mcap);
            update2T_k<<<KC, 128, 0, stream>>>(XsT, offp, counts, cc, cn, csn,
                                               conv, t, mcap);
        } else {
            updateg_k<<<KC, 128, 0, stream>>>(X, srcidx, offp, counts, cc, cn,
                                              csn, conv, t);
        }
    }
    final_k<<<KC * ND / 256, 256, 0, stream>>>(centb, conv, outF);
}

// Round 9
// 2019.771 us; speedup vs baseline: 1.2382x; 1.2382x over previous
//
#include <hip/hip_runtime.h>
#include <math.h>

// K-means m=100000, n=128, K=128, 15 iters, tol=1e-4 — bit-exact f32 replication
// of the numpy reference arithmetic (verified absmax 0.0 in R3-R8):
//  - dots: sequential in-order FMA chain over d (ascending)
//  - x_sq/c_sq/norm: numpy pairwise-8 pattern
//  - d2 = (x_sq - 2*dot) + c_sq, each op individually rounded (__f*_rn)
//  - argmin: first-min-wins; segment sums: sequential adds in ascending point order
// R9: update reworked. R8's transposed layout made every load a 64-lane scatter
// (lanes 400KB apart -> 213GB/s). Now: row-major sorted Xs (sortx = coalesced
// copy); update chain reads rows (512B contiguous/block), 16-row batches in
// named A-D reg buffers, 4-deep pipeline with counted s_waitcnt vmcnt(48)
// (T4) + sched_barrier (rule #18); masked 64-row tail (exact +0.0 pads).

#define KC 128
#define ND 128

__device__ __forceinline__ unsigned mapf(float s) {
    unsigned b = __float_as_uint(s);
    return (b & 0x80000000u) ? ~b : (b | 0x80000000u);  // order-preserving f32->u32
}

__device__ __forceinline__ bool is_done(const int* __restrict__ conv, int t) {
    bool d = false;
    for (int j = 0; j < t; ++j) d |= (conv[j] == KC);
    return d;
}

// numpy pairwise-8 combine tree
__device__ __forceinline__ float comb8(const float* r) {
    float t1 = __fadd_rn(__fadd_rn(r[0], r[1]), __fadd_rn(r[2], r[3]));
    float t2 = __fadd_rn(__fadd_rn(r[4], r[5]), __fadd_rn(r[6], r[7]));
    return __fadd_rn(t1, t2);
}

// ---- x_sq per point (once): numpy pairwise-8 over rounded squares ----
__global__ __launch_bounds__(256) void xsq_k(const float* __restrict__ X,
                                             float* __restrict__ xsq, int m) {
    int p = blockIdx.x * 256 + threadIdx.x;
    if (p >= m) return;
    const float* xr = X + (size_t)p * ND;
    float r[8];
#pragma unroll
    for (int j = 0; j < 8; ++j) r[j] = __fmul_rn(xr[j], xr[j]);
    for (int b = 1; b < 16; ++b) {
#pragma unroll
        for (int j = 0; j < 8; ++j) {
            float v = xr[8 * b + j];
            r[j] = __fadd_rn(r[j], __fmul_rn(v, v));
        }
    }
    xsq[p] = comb8(r);
}

// ---- csq of initial centroids ----
__global__ __launch_bounds__(128) void csq0_k(const float* __restrict__ c,
                                              float* __restrict__ csq) {
    int k = threadIdx.x;
    const float* cr = c + k * ND;
    float r[8];
#pragma unroll
    for (int j = 0; j < 8; ++j) r[j] = __fmul_rn(cr[j], cr[j]);
    for (int b = 1; b < 16; ++b) {
#pragma unroll
        for (int j = 0; j < 8; ++j) {
            float v = cr[8 * b + j];
            r[j] = __fadd_rn(r[j], __fmul_rn(v, v));
        }
    }
    csq[k] = comb8(r);
}

// ---- assign: grid ceil(m/128), block 256. One pass, 128pt x 128k tile ----
__global__ __launch_bounds__(256, 3) void assign_k(
    const float* __restrict__ X, const float* __restrict__ cent,
    const float* __restrict__ csq, const float* __restrict__ xsq,
    int* __restrict__ cl, float* __restrict__ cl_out,
    unsigned char* __restrict__ rankA, unsigned char* __restrict__ hist,
    const int* __restrict__ conv, int t, int m, int nch)
{
    if (is_done(conv, t)) return;
    __shared__ float XT[32][128];    // [d'][pt]  16 KB
    __shared__ float CT[128][36];    // [k][d']   18 KB
    __shared__ float csql[128];
    __shared__ unsigned long long mk[128];
    __shared__ int cls[128];

    const int tid = threadIdx.x;
    const int ptg = tid & 31, kg = tid >> 5;
    const int base = blockIdx.x * 128;
    const int row = tid >> 1, hf = tid & 1;      // staging coords

    if (tid < 128) { mk[tid] = ~0ULL; csql[tid] = csq[tid]; }

    const int srow = base + row;
    const float4* xsrc = (const float4*)(X + (size_t)(srow < m ? srow : m - 1) * ND);
    const float4* csrc = (const float4*)(cent + (size_t)row * ND);

    float acc[4][16];
#pragma unroll
    for (int i = 0; i < 4; ++i)
#pragma unroll
        for (int j = 0; j < 16; ++j) acc[i][j] = 0.0f;

    float4 xr[4], cr[4];
#pragma unroll
    for (int q = 0; q < 4; ++q) {                // prefetch chunk 0
        xr[q] = xsrc[hf * 4 + q];
        cr[q] = csrc[hf * 4 + q];
    }

#pragma unroll 1
    for (int c = 0; c < 4; ++c) {
        __syncthreads();                         // prior compute done
#pragma unroll
        for (int q = 0; q < 4; ++q) {            // store regs -> LDS
            const int dp = hf * 16 + 4 * q;      // d' within chunk
            XT[dp + 0][row] = xr[q].x;
            XT[dp + 1][row] = xr[q].y;
            XT[dp + 2][row] = xr[q].z;
            XT[dp + 3][row] = xr[q].w;
            *(float4*)&CT[row][dp] = cr[q];
        }
        __syncthreads();
        if (c < 3) {
#pragma unroll
            for (int q = 0; q < 4; ++q) {        // prefetch chunk c+1
                xr[q] = xsrc[(c + 1) * 8 + hf * 4 + q];
                cr[q] = csrc[(c + 1) * 8 + hf * 4 + q];
            }
        }
#pragma unroll
        for (int c4 = 0; c4 < 8; ++c4) {         // 4 ds per step, ascending
            float4 av[4];
#pragma unroll
            for (int dd = 0; dd < 4; ++dd)
                av[dd] = *(const float4*)&XT[4 * c4 + dd][4 * ptg];
#pragma unroll
            for (int j = 0; j < 16; ++j) {
                const float4 b = *(const float4*)&CT[kg * 16 + j][4 * c4];
#pragma unroll
                for (int i = 0; i < 4; ++i) {
                    float s = acc[i][j];
                    const float a0 = (i == 0) ? av[0].x : (i == 1) ? av[0].y
                                   : (i == 2) ? av[0].z : av[0].w;
                    const float a1 = (i == 0) ? av[1].x : (i == 1) ? av[1].y
                                   : (i == 2) ? av[1].z : av[1].w;
                    const float a2 = (i == 0) ? av[2].x : (i == 1) ? av[2].y
                                   : (i == 2) ? av[2].z : av[2].w;
                    const float a3 = (i == 0) ? av[3].x : (i == 1) ? av[3].y
                                   : (i == 2) ? av[3].z : av[3].w;
                    s = __fmaf_rn(a0, b.x, s);
                    s = __fmaf_rn(a1, b.y, s);
                    s = __fmaf_rn(a2, b.z, s);
                    s = __fmaf_rn(a3, b.w, s);
                    acc[i][j] = s;
                }
            }
        }
    }

    // ---- per-point argmin over this thread's 16 ks, then cross-thread ----
#pragma unroll
    for (int i = 0; i < 4; ++i) {
        const int pt = base + 4 * ptg + i;
        if (pt >= m) continue;
        const float xq = xsq[pt];
        float best = __int_as_float(0x7f800000);
        int bk = 0;
#pragma unroll
        for (int j = 0; j < 16; ++j) {           // ascending k
            const int kk = kg * 16 + j;
            const float d2 =
                __fadd_rn(__fsub_rn(xq, __fmul_rn(2.0f, acc[i][j])), csql[kk]);
            if (d2 < best) { best = d2; bk = kk; }
        }
        const unsigned long long key =
            ((unsigned long long)mapf(best) << 32) | (unsigned)bk;
        atomicMin(&mk[4 * ptg + i], key);
    }
    __syncthreads();
    if (tid < 128) {
        const int pt = base + tid;
        int k = 255;
        if (pt < m) {
            k = (int)(mk[tid] & 0xFFFFFFFFu);
            cl[pt] = k;
            cl_out[pt] = (float)k;
        }
        cls[tid] = k;
    }
    __syncthreads();
    // ---- fused stable rank (waves 0-1) + per-chunk histogram (waves 2-3) ----
    if (tid < 128) {
        const int myc = cls[tid];
        int rank = 0;
        for (int q = 0; q < 128; ++q)
            rank += (q < tid && cls[q] == myc) ? 1 : 0;
        if (base + tid < m) rankA[base + tid] = (unsigned char)rank;
    } else {
        const int c = tid - 128;
        int cnt = 0;
        for (int q = 0; q < 128; ++q)
            cnt += (cls[q] == c) ? 1 : 0;
        hist[(size_t)c * nch + blockIdx.x] = (unsigned char)cnt;
    }
}

// ---- per-cluster prefix over chunks: block k, 256 threads ----
__global__ __launch_bounds__(256) void scan_k(
    const unsigned char* __restrict__ hist, unsigned* __restrict__ cbase,
    int* __restrict__ counts, const int* __restrict__ conv, int t, int nch)
{
    if (is_done(conv, t)) return;
    const int k = blockIdx.x, tid = threadIdx.x;
    const int strip = (nch + 255) >> 8;
    __shared__ int ss[256];
    int s = 0;
    for (int j = 0; j < strip; ++j) {
        int c = tid * strip + j;
        if (c < nch) s += hist[(size_t)k * nch + c];
    }
    ss[tid] = s;
    __syncthreads();
    if (tid == 0) {
        int run = 0;
        for (int i = 0; i < 256; ++i) { int v = ss[i]; ss[i] = run; run += v; }
        counts[k] = run;
    }
    __syncthreads();
    int run = ss[tid];
    for (int j = 0; j < strip; ++j) {
        int c = tid * strip + j;
        if (c < nch) {
            cbase[(size_t)k * nch + c] = (unsigned)run;
            run += hist[(size_t)k * nch + c];
        }
    }
}

// ---- padded offsets (np4 = roundup4) + pad fill + tail fill ----
__global__ __launch_bounds__(128) void off_k(
    const int* __restrict__ counts, int* __restrict__ offp,
    int* __restrict__ srcidx, const int* __restrict__ conv, int t, int mcap)
{
    if (is_done(conv, t)) return;
    __shared__ int o[KC + 1];
    if (threadIdx.x == 0) {
        int run = 0;
        for (int k = 0; k < KC; ++k) { o[k] = run; run += (counts[k] + 3) & ~3; }
        o[KC] = run;
        offp[KC] = run;
    }
    __syncthreads();
    const int k = threadIdx.x;
    offp[k] = o[k];
    const int n = counts[k], np = (n + 3) & ~3;
    for (int i = n; i < np; ++i) srcidx[o[k] + i] = -1;
    for (int i = o[KC] + k; i < mcap; i += 128) srcidx[i] = -1;
}

// ---- scatter point ids into padded stable-sorted positions ----
__global__ __launch_bounds__(256) void scatter_k(
    const int* __restrict__ cl, const unsigned char* __restrict__ rankA,
    const unsigned* __restrict__ cbase, const int* __restrict__ offp,
    int* __restrict__ srcidx, const int* __restrict__ conv,
    int t, int m, int nch)
{
    if (is_done(conv, t)) return;
    int p = blockIdx.x * 256 + threadIdx.x;
    if (p >= m) return;
    int c = cl[p];
    int chunk = p >> 7;                          // 128-pt chunks
    srcidx[offp[c] + (int)cbase[(size_t)c * nch + chunk] + rankA[p]] = p;
}

// ---- materialize row-major sorted Xs (coalesced copy; pads -> +0.0 rows) ----
__global__ __launch_bounds__(256) void sortx_k(
    const float* __restrict__ X, const int* __restrict__ srcidx,
    float* __restrict__ Xs, const int* __restrict__ conv, int t, int mcap)
{
    if (is_done(conv, t)) return;
    const int s = blockIdx.x * 8 + (threadIdx.x >> 5);
    if (s >= mcap) return;
    const int q = threadIdx.x & 31;
    const int src = srcidx[s];
    float4 v = make_float4(0.f, 0.f, 0.f, 0.f);
    if (src >= 0) v = ((const float4*)(X + (size_t)src * ND))[q];
    ((float4*)(Xs + (size_t)s * ND))[q] = v;
}

// ---- shared epilogue of the update kernels ----
__device__ __forceinline__ void update_epi(
    int k, int d, int n, float s,
    const float* __restrict__ cent_old, float* __restrict__ cent_new,
    float* __restrict__ csq_new, int* __restrict__ conv, int t)
{
    const float old = cent_old[k * ND + d];
    const float nv = (n > 0) ? __fdiv_rn(s, (float)n) : old;
    cent_new[k * ND + d] = nv;

    __shared__ float sv[128], dv[128], rr[8], dd[8];
    sv[d] = nv;
    dv[d] = __fsub_rn(nv, old);
    __syncthreads();
    if (d < 8) {
        float r = __fmul_rn(sv[d], sv[d]);
        float q = __fmul_rn(dv[d], dv[d]);
        for (int b = 1; b < 16; ++b) {
            float c1 = sv[8 * b + d], c2 = dv[8 * b + d];
            r = __fadd_rn(r, __fmul_rn(c1, c1));
            q = __fadd_rn(q, __fmul_rn(c2, c2));
        }
        rr[d] = r; dd[d] = q;
    }
    __syncthreads();
    if (d == 0) {
        csq_new[k] = comb8(rr);
        float ns = comb8(dd);
        if (__fsqrt_rn(ns) < 1e-4f) atomicAdd(&conv[t], 1);
    }
}

// one pinned coalesced dword load, dest named reg, compiler can't sink/merge
#define G1(dst, ptr, OFF) \
    asm volatile("global_load_dword %0, %1, off offset:" #OFF \
                 : "=&v"(dst) : "v"(ptr))

// issue 16 rows (stride 512B) from base p (2 bases: offsets cap at 4095)
#define ISSUE(B, p) do {                                                   \
    const char* q_ = (p) + 4096;                                           \
    G1(B[0],  p,  0);    G1(B[1],  p,  512);  G1(B[2],  p,  1024);         \
    G1(B[3],  p,  1536); G1(B[4],  p,  2048); G1(B[5],  p,  2560);         \
    G1(B[6],  p,  3072); G1(B[7],  p,  3584);                              \
    G1(B[8],  q_, 0);    G1(B[9],  q_, 512);  G1(B[10], q_, 1024);         \
    G1(B[11], q_, 1536); G1(B[12], q_, 2048); G1(B[13], q_, 2560);         \
    G1(B[14], q_, 3072); G1(B[15], q_, 3584);                              \
} while (0)

#define WAITV(N) do {                                                      \
    asm volatile("s_waitcnt vmcnt(" #N ")" ::: "memory");                  \
    __builtin_amdgcn_sched_barrier(0);                                     \
} while (0)

#define ADD16(B) do {                                                      \
    s = __fadd_rn(s, B[0]);  s = __fadd_rn(s, B[1]);                       \
    s = __fadd_rn(s, B[2]);  s = __fadd_rn(s, B[3]);                       \
    s = __fadd_rn(s, B[4]);  s = __fadd_rn(s, B[5]);                       \
    s = __fadd_rn(s, B[6]);  s = __fadd_rn(s, B[7]);                       \
    s = __fadd_rn(s, B[8]);  s = __fadd_rn(s, B[9]);                       \
    s = __fadd_rn(s, B[10]); s = __fadd_rn(s, B[11]);                      \
    s = __fadd_rn(s, B[12]); s = __fadd_rn(s, B[13]);                      \
    s = __fadd_rn(s, B[14]); s = __fadd_rn(s, B[15]);                      \
} while (0)

// masked adds for the final 64-row block: rows >= np4 contribute exact +0.0
#define ADD16M(B, BASE) do {                                               \
    _Pragma("unroll")                                                      \
    for (int j_ = 0; j_ < 16; ++j_) {                                      \
        float vv = ((BASE) + j_ < np4) ? B[j_] : 0.0f;                     \
        s = __fadd_rn(s, vv);                                              \
    }                                                                      \
} while (0)

// ---- segment mean: coalesced rows, 4-deep counted-vmcnt pipeline ----
__global__ __launch_bounds__(128) void updateS_k(
    const float* __restrict__ Xs, const int* __restrict__ offp,
    const int* __restrict__ counts, const float* __restrict__ cent_old,
    float* __restrict__ cent_new, float* __restrict__ csq_new,
    int* __restrict__ conv, int t)
{
    if (is_done(conv, t)) return;
    const int k = blockIdx.x, d = threadIdx.x;
    const int n = counts[k];
    float s = 0.0f;
    if (n > 0) {
        const int np4 = (n + 3) & ~3;            // zeros stored up to np4
        const int R0 = n & ~63;                  // full-64 row prefix
        const char* p = (const char*)(Xs + (size_t)offp[k] * ND + d);
        float A[16], B[16], C[16], D[16];
        if (R0 > 0) {
            const int nb = R0 >> 4;              // mult of 4, >= 4
            ISSUE(A, p); p += 8192;
            ISSUE(B, p); p += 8192;
            ISSUE(C, p); p += 8192;
            ISSUE(D, p); p += 8192;
#pragma unroll 1
            for (int b = 0; b < nb - 4; b += 4) {
                WAITV(48); ADD16(A); ISSUE(A, p); p += 8192;
                WAITV(48); ADD16(B); ISSUE(B, p); p += 8192;
                WAITV(48); ADD16(C); ISSUE(C, p); p += 8192;
                WAITV(48); ADD16(D); ISSUE(D, p); p += 8192;
            }
            // rows R0-64..R0-1 in flight; add them while issuing tail block
            WAITV(48); ADD16(A); ISSUE(A, p); p += 8192;
            WAITV(48); ADD16(B); ISSUE(B, p); p += 8192;
            WAITV(48); ADD16(C); ISSUE(C, p); p += 8192;
            WAITV(48); ADD16(D); ISSUE(D, p); p += 8192;
        } else {
            ISSUE(A, p); p += 8192;
            ISSUE(B, p); p += 8192;
            ISSUE(C, p); p += 8192;
            ISSUE(D, p); p += 8192;
        }
        // drain tail block rows R0..R0+63 with np4 masking (reads stay in Xs)
        WAITV(48); ADD16M(A, R0 + 0);
        WAITV(32); ADD16M(B, R0 + 16);
        WAITV(16); ADD16M(C, R0 + 32);
        WAITV(0);  ADD16M(D, R0 + 48);
    }
    update_epi(k, d, n, s, cent_old, cent_new, csq_new, conv, t);
}

// ---- fallback (small ws): gather via srcidx ----
__global__ __launch_bounds__(128) void updateg_k(
    const float* __restrict__ X, const int* __restrict__ srcidx,
    const int* __restrict__ offp, const int* __restrict__ counts,
    const float* __restrict__ cent_old, float* __restrict__ cent_new,
    float* __restrict__ csq_new, int* __restrict__ conv, int t)
{
    if (is_done(conv, t)) return;
    const int k = blockIdx.x, d = threadIdx.x;
    const int n = counts[k];
    const int npad = (n + 3) & ~3;
    const int* si = srcidx + offp[k];
    float s = 0.0f;
#pragma unroll 1
    for (int i0 = 0; i0 < npad; i0 += 32) {
        float v[32];
#pragma unroll
        for (int j = 0; j < 32; ++j) {
            int idx = i0 + j;
            int src = idx < npad ? si[idx] : -1;
            float x = X[(size_t)(src < 0 ? 0 : src) * ND + d];
            v[j] = (src >= 0 && idx < npad) ? x : 0.0f;
        }
        __builtin_amdgcn_sched_barrier(0);
#pragma unroll
        for (int j = 0; j < 32; ++j) s = __fadd_rn(s, v[j]);
    }
    update_epi(k, d, n, s, cent_old, cent_new, csq_new, conv, t);
}

// ---- final: pick the right centroid buffer ----
__global__ __launch_bounds__(256) void final_k(
    const float* __restrict__ cent_bufs, const int* __restrict__ conv,
    float* __restrict__ out)
{
    int tf = 15;
    for (int j = 14; j >= 0; --j)
        if (conv[j] == KC) tf = j;
    const float* c = cent_bufs + (size_t)(tf & 1) * KC * ND;
    int i = blockIdx.x * 256 + threadIdx.x;
    out[i] = c[i];
}

extern "C" void kernel_launch(void* const* d_in, const int* in_sizes, int n_in,
                              void* d_out, int out_size, void* d_ws, size_t ws_size,
                              hipStream_t stream) {
    const float* X = (const float*)d_in[0];
    const float* cent0 = (const float*)d_in[1];
    float* outF = (float*)d_out;
    const int m = in_sizes[0] / ND;              // 100000
    const int nch = (m + 127) / 128;             // 782 chunks of 128 pts
    // np4 padding + 64-row tail-read slack, rounded to 128 rows
    const int mcap = ((m + 4 * KC + 64) + 127) & ~127;

    unsigned char* w = (unsigned char*)d_ws;
    float* centb = (float*)w;            w += (size_t)2 * KC * ND * 4;
    float* csqb = (float*)w;             w += (size_t)2 * KC * 4;
    float* xsq = (float*)w;              w += (size_t)m * 4;
    int* cl = (int*)w;                   w += (size_t)m * 4;
    int* srcidx = (int*)w;               w += (size_t)mcap * 4;
    unsigned* cbase = (unsigned*)w;      w += (size_t)KC * nch * 4;
    int* offp = (int*)w;                 w += 132 * 4;
    int* counts = (int*)w;               w += KC * 4;
    int* conv = (int*)w;                 w += 16 * 4;
    unsigned char* rankA = w;            w += (size_t)m;
    unsigned char* hist = w;             w += (size_t)KC * nch;
    w = (unsigned char*)(((uintptr_t)w + 15) & ~(uintptr_t)15);
    float* Xs = (float*)w;               // ND * mcap floats (~51.5 MB)
    const bool use_t =
        ((unsigned char*)Xs - (unsigned char*)d_ws) + (size_t)ND * mcap * 4 <= ws_size;

    hipMemsetAsync(conv, 0, 16 * sizeof(int), stream);
    hipMemcpyAsync(centb, cent0, KC * ND * sizeof(float),
                   hipMemcpyDeviceToDevice, stream);
    csq0_k<<<1, 128, 0, stream>>>(centb, csqb);

    const int gp = (m + 255) / 256;              // 391
    const int ga = (m + 127) / 128;              // 782
    const int gs = mcap / 8;                     // sortx blocks (8 rows each)
    xsq_k<<<gp, 256, 0, stream>>>(X, xsq, m);

    for (int t = 0; t < 15; ++t) {
        const float* cc = centb + (size_t)(t & 1) * KC * ND;
        float* cn = centb + (size_t)((t + 1) & 1) * KC * ND;
        const float* cs = csqb + (t & 1) * KC;
        float* csn = csqb + ((t + 1) & 1) * KC;

        assign_k<<<ga, 256, 0, stream>>>(X, cc, cs, xsq, cl, outF + KC * ND,
                                         rankA, hist, conv, t, m, nch);
        scan_k<<<KC, 256, 0, stream>>>(hist, cbase, counts, conv, t, nch);
        off_k<<<1, 128, 0, stream>>>(counts, offp, srcidx, conv, t, mcap);
        scatter_k<<<gp, 256, 0, stream>>>(cl, rankA, cbase, offp, srcidx,
                                          conv, t, m, nch);
        if (use_t) {
            sortx_k<<<gs, 256, 0, stream>>>(X, srcidx, Xs, conv, t, mcap);
            updateS_k<<<KC, 128, 0, stream>>>(Xs, offp, counts, cc, cn, csn,
                                              conv, t);
        } else {
            updateg_k<<<KC, 128, 0, stream>>>(X, srcidx, offp, counts, cc, cn,
                                              csn, conv, t);
        }
    }
    final_k<<<KC * ND / 256, 256, 0, stream>>>(centb, conv, outF);
}